// Round 1
// baseline (205.581 us; speedup 1.0000x reference)
//
#include <hip/hip_runtime.h>

typedef unsigned int u32;
typedef unsigned long long u64;

#define NB 32
#define NCLS 80
#define NANCHOR 8400
#define PRE 1000
#define MAXDET 100
#define NT 1024

// ---------------------------------------------------------------------------
// Kernel 1: decode all levels. One thread per (image, anchor).
// Writes scores[32][8400], boxes[32][8400][4], cls[32][8400] to workspace.
// ---------------------------------------------------------------------------
__global__ void decode_kernel(const float* __restrict__ cls0, const float* __restrict__ box0,
                              const float* __restrict__ cls1, const float* __restrict__ box1,
                              const float* __restrict__ cls2, const float* __restrict__ box2,
                              float* __restrict__ ws_scores, float4* __restrict__ ws_boxes,
                              int* __restrict__ ws_cls) {
    int g = blockIdx.x * blockDim.x + threadIdx.x;
    if (g >= NB * NANCHOR) return;
    int b = g / NANCHOR;
    int r = g - b * NANCHOR;

    const float* cp; const float* bp;
    int HW, hw, h, w, step;
    if (r < 6400) {
        cp = cls0 + (size_t)b * NCLS * 6400; bp = box0 + (size_t)b * 4 * 6400;
        HW = 6400; hw = r;        h = hw / 80; w = hw - h * 80; step = 8;
    } else if (r < 8000) {
        cp = cls1 + (size_t)b * NCLS * 1600; bp = box1 + (size_t)b * 4 * 1600;
        HW = 1600; hw = r - 6400; h = hw / 40; w = hw - h * 40; step = 16;
    } else {
        cp = cls2 + (size_t)b * NCLS * 400;  bp = box2 + (size_t)b * 4 * 400;
        HW = 400;  hw = r - 8000; h = hw / 20; w = hw - h * 20; step = 32;
    }

    // argmax over class logits (== argmax over sigmoid, monotone; first-max like np.argmax)
    float m = cp[hw];
    int ci = 0;
    for (int c = 1; c < NCLS; ++c) {
        float v = cp[(size_t)c * HW + hw];
        if (v > m) { m = v; ci = c; }
    }
    float score = 1.0f / (1.0f + expf(-m));   // sigmoid(max logit) == max(sigmoid)

    float l = bp[hw], t = bp[HW + hw], rr = bp[2 * HW + hw], bo = bp[3 * HW + hw];
    float gx = (float)(w * step), gy = (float)(h * step);

    ws_scores[g] = score;
    ws_boxes[g] = make_float4(gx - l, gy - t, gx + rr, gy + bo);
    ws_cls[g] = ci;
}

// ---------------------------------------------------------------------------
// Kernel 2: per-image (one block of 1024 threads): radix-select top candidates,
// bitonic-sort them (score desc, idx asc), greedy class-aware NMS with early
// exit at 100 survivors, write outputs.
// ---------------------------------------------------------------------------
__global__ __launch_bounds__(NT) void nms_kernel(const float* __restrict__ ws_scores,
                                                 const float4* __restrict__ ws_boxes,
                                                 const int* __restrict__ ws_cls,
                                                 float* __restrict__ out) {
    const int b = blockIdx.x;
    const int tid = threadIdx.x;

    __shared__ int s_hist[1024];
    __shared__ u64 s_key[2048];
    __shared__ float s_x1[PRE], s_y1[PRE], s_x2[PRE], s_y2[PRE], s_area[PRE];
    __shared__ int s_supp[PRE];
    __shared__ int s_keep[MAXDET];
    __shared__ int s_C, s_base;
    __shared__ u32 s_thresh;
    __shared__ int s_cnt;

    const float* sc = ws_scores + (size_t)b * NANCHOR;

    // ---- pass 1: coarse histogram on score bits [29:20] (scores in (0,1) -> bits < 2^30)
    s_hist[tid] = 0;
    __syncthreads();
    for (int a = tid; a < NANCHOR; a += NT) {
        u32 sb = __float_as_uint(sc[a]);
        atomicAdd(&s_hist[sb >> 20], 1);
    }
    __syncthreads();
    // suffix scan (Hillis-Steele, in place with double barrier)
    for (int off = 1; off < 1024; off <<= 1) {
        int v = s_hist[tid];
        int u = (tid + off < 1024) ? s_hist[tid + off] : 0;
        __syncthreads();
        s_hist[tid] = v + u;
        __syncthreads();
    }
    {
        int sfx = s_hist[tid];
        int nxt = (tid < 1023) ? s_hist[tid + 1] : 0;
        if (sfx >= PRE && (tid == 1023 || nxt < PRE)) { s_C = tid; s_base = nxt; }
    }
    __syncthreads();
    const int C = s_C, base = s_base;
    __syncthreads();

    // ---- pass 2: fine histogram on bits [19:10] within coarse bin C
    s_hist[tid] = 0;
    __syncthreads();
    for (int a = tid; a < NANCHOR; a += NT) {
        u32 sb = __float_as_uint(sc[a]);
        if ((int)(sb >> 20) == C) atomicAdd(&s_hist[(sb >> 10) & 1023], 1);
    }
    __syncthreads();
    for (int off = 1; off < 1024; off <<= 1) {
        int v = s_hist[tid];
        int u = (tid + off < 1024) ? s_hist[tid + off] : 0;
        __syncthreads();
        s_hist[tid] = v + u;
        __syncthreads();
    }
    {
        int sfx = base + s_hist[tid];
        int nxt = base + ((tid < 1023) ? s_hist[tid + 1] : 0);
        if (sfx >= PRE && (tid == 1023 || nxt < PRE))
            s_thresh = ((u32)C << 20) | ((u32)tid << 10);
    }
    if (tid == 0) s_cnt = 0;
    s_key[tid] = 0ULL;
    s_key[tid + 1024] = 0ULL;
    __syncthreads();
    const u32 thresh = s_thresh;

    // ---- compaction: all elements with scorebits >= thresh (prefix-closed set, >= 1000)
    for (int a = tid; a < NANCHOR; a += NT) {
        u32 sb = __float_as_uint(sc[a]);
        if (sb >= thresh) {
            int pos = atomicAdd(&s_cnt, 1);
            if (pos < 2048)
                s_key[pos] = ((u64)sb << 14) | (u64)(NANCHOR - 1 - a);  // desc score, asc idx
        }
    }
    __syncthreads();

    // ---- bitonic sort 2048 keys, descending (pads = 0 sink to the end)
    for (int k = 2; k <= 2048; k <<= 1) {
        for (int j = k >> 1; j > 0; j >>= 1) {
            for (int i = tid; i < 2048; i += NT) {
                int ixj = i ^ j;
                if (ixj > i) {
                    u64 va = s_key[i], vb = s_key[ixj];
                    bool desc = ((i & k) == 0);
                    if (desc ? (va < vb) : (va > vb)) { s_key[i] = vb; s_key[ixj] = va; }
                }
            }
            __syncthreads();
        }
    }

    // ---- load top-1000 into LDS with class offset applied (reference fp32 op order)
    if (tid < PRE) {
        u64 key = s_key[tid];
        int idx = (NANCHOR - 1) - (int)(key & 16383ULL);
        float4 bx = ws_boxes[(size_t)b * NANCHOR + idx];
        int c = ws_cls[(size_t)b * NANCHOR + idx];
        float off = (float)c * 4096.0f;
        float x1 = bx.x + off, y1 = bx.y + off, x2 = bx.z + off, y2 = bx.w + off;
        s_x1[tid] = x1; s_y1[tid] = y1; s_x2[tid] = x2; s_y2[tid] = y2;
        s_area[tid] = fmaxf(x2 - x1, 0.0f) * fmaxf(y2 - y1, 0.0f);
        s_supp[tid] = 0;
    }
    __syncthreads();

    // ---- greedy NMS. Early exit at 100 survivors: rows after the 100th survivor
    // can only suppress lower-ranked rows, which never appear in the output.
    int nkept = 0;
    for (int i = 0; i < PRE; ++i) {
        if (s_supp[i]) continue;          // uniform read; no writes since last barrier
        if (tid == 0) s_keep[nkept] = i;
        nkept++;
        if (nkept >= MAXDET) break;
        float xi1 = s_x1[i], yi1 = s_y1[i], xi2 = s_x2[i], yi2 = s_y2[i], ai = s_area[i];
        int j = i + 1 + tid;              // NT >= PRE, so one j per thread
        if (j < PRE && !s_supp[j]) {
            float lx = fmaxf(xi1, s_x1[j]);
            float ly = fmaxf(yi1, s_y1[j]);
            float rx = fminf(xi2, s_x2[j]);
            float ry = fminf(yi2, s_y2[j]);
            float wx = fmaxf(rx - lx, 0.0f);
            float wy = fmaxf(ry - ly, 0.0f);
            float inter = wx * wy;
            float iou = inter / (ai + s_area[j] - inter + 1e-7f); // ((ai+aj)-inter)+eps
            if (iou > 0.5f) s_supp[j] = 1;
        }
        __syncthreads();
    }
    __syncthreads();

    // ---- outputs: boxes_with_scores [32][100][5], then classes [32][100] (as float)
    if (tid < MAXDET) {
        float* o = out + ((size_t)b * MAXDET + tid) * 5;
        float* oc = out + (size_t)NB * MAXDET * 5 + (size_t)b * MAXDET + tid;
        if (tid < nkept) {
            int i = s_keep[tid];
            u64 key = s_key[i];
            int idx = (NANCHOR - 1) - (int)(key & 16383ULL);
            float score = __uint_as_float((u32)(key >> 14));
            float4 bx = ws_boxes[(size_t)b * NANCHOR + idx];
            int c = ws_cls[(size_t)b * NANCHOR + idx];
            o[0] = bx.x; o[1] = bx.y; o[2] = bx.z; o[3] = bx.w; o[4] = score;
            *oc = (float)c;
        } else {
            o[0] = 0.0f; o[1] = 0.0f; o[2] = 0.0f; o[3] = 0.0f; o[4] = 0.0f;
            *oc = -1.0f;
        }
    }
}

extern "C" void kernel_launch(void* const* d_in, const int* in_sizes, int n_in,
                              void* d_out, int out_size, void* d_ws, size_t ws_size,
                              hipStream_t stream) {
    const float* cls0 = (const float*)d_in[0];
    const float* box0 = (const float*)d_in[1];
    const float* cls1 = (const float*)d_in[2];
    const float* box1 = (const float*)d_in[3];
    const float* cls2 = (const float*)d_in[4];
    const float* box2 = (const float*)d_in[5];

    float* ws = (float*)d_ws;
    float* ws_scores = ws;                                   // 268800 floats
    float4* ws_boxes = (float4*)(ws + NB * NANCHOR);         // 268800 float4 (16B aligned)
    int* ws_cls = (int*)(ws + (size_t)NB * NANCHOR * 5);     // 268800 ints

    int total = NB * NANCHOR;
    decode_kernel<<<(total + 255) / 256, 256, 0, stream>>>(
        cls0, box0, cls1, box1, cls2, box2, ws_scores, ws_boxes, ws_cls);

    nms_kernel<<<NB, NT, 0, stream>>>(ws_scores, ws_boxes, ws_cls, (float*)d_out);
}